// Round 1
// baseline (44.663 us; speedup 1.0000x reference)
//
#include <hip/hip_runtime.h>
#include <math.h>

// out[b,i,j,d,f] = valid(i1,j1) ? x[b, iy(i1,j1), ix(i1,j1), 127-d, f] : 0
//   i1 = (i-7) & 127          (inverse of roll +7 on H)
//   j1 = (140-j) & 127        (inverse of roll -13 on W composed with W-flip)
//   dsrc = 127 - d            (D-flip)
//   (iy,ix) = nearest-neighbor rotation source, float32 math matching jnp.

__global__ __launch_bounds__(256) void Augment_77532749627421_kernel(
    const float* __restrict__ x, float* __restrict__ out,
    const float c, const float s, const long total4)
{
    const float cc = 63.5f;  // (H-1)*0.5 == (W-1)*0.5
    long idx    = (long)blockIdx.x * blockDim.x + threadIdx.x;
    long stride = (long)gridDim.x * blockDim.x;
    for (long o4 = idx; o4 < total4; o4 += stride) {
        int f4 = (int)(o4 & 1);          // which float4 within F=8
        int d  = (int)((o4 >> 1) & 127);
        int j  = (int)((o4 >> 8) & 127);
        int i  = (int)((o4 >> 15) & 127);
        int b  = (int)(o4 >> 22);

        int i1 = (i - 7) & 127;
        int j1 = (140 - j) & 127;

        // Bit-exact mirror of the reference's f32 ops (no FMA contraction):
        // sx = c*dx - s*dy + cx ; sy = s*dx + c*dy + cy
        float dx = (float)j1 - cc;
        float dy = (float)i1 - cc;
        float sx = __fadd_rn(__fsub_rn(__fmul_rn(c, dx), __fmul_rn(s, dy)), cc);
        float sy = __fadd_rn(__fadd_rn(__fmul_rn(s, dx), __fmul_rn(c, dy)), cc);
        int ix = (int)rintf(sx);   // rint = round-half-even, matches jnp.round
        int iy = (int)rintf(sy);

        float4 v = make_float4(0.f, 0.f, 0.f, 0.f);
        if (((unsigned)ix < 128u) && ((unsigned)iy < 128u)) {
            int dsrc = 127 - d;
            long src4 = ((((long)b * 128 + iy) * 128 + ix) * 128 + dsrc) * 2 + f4;
            v = ((const float4*)x)[src4];
        }
        ((float4*)out)[o4] = v;
    }
}

extern "C" void kernel_launch(void* const* d_in, const int* in_sizes, int n_in,
                              void* d_out, int out_size, void* d_ws, size_t ws_size,
                              hipStream_t stream) {
    const float* x = (const float*)d_in[0];
    float* out = (float*)d_out;

    // theta = jnp.deg2rad(jnp.float32(80)) in f32: f32(80) * f32(pi/180)
    float deg2rad_c = (float)(M_PI / 180.0);
    float theta = 80.0f * deg2rad_c;
    // correctly-rounded f32 cos/sin of the f32 theta
    float c = (float)cos((double)theta);
    float s = (float)sin((double)theta);

    long total4 = (long)out_size / 4;   // 2*128*128*128*8 / 4 = 2^23
    int block = 256;
    int grid = 2048;                    // grid-stride, ~8 blocks/CU
    hipLaunchKernelGGL(Augment_77532749627421_kernel, dim3(grid), dim3(block), 0, stream,
                       x, out, c, s, total4);
}

// Round 3
// 42.224 us; speedup vs baseline: 1.0578x; 1.0578x over previous
//
#include <hip/hip_runtime.h>
#include <math.h>

// out[b,i,j,d,f] = valid(i1,j1) ? x[b, iy(i1,j1), ix(i1,j1), 127-d, f] : 0
//   i1 = (i-7) & 127          (inverse of roll +7 on H)
//   j1 = (140-j) & 127        (inverse of roll -13 on W composed with W-flip)
//   dsrc = 127 - d            (D-flip)
// Rotation source math replicates jnp float32 ops exactly (no FMA contraction,
// rintf = round-half-even like jnp.round).

typedef float f32x4 __attribute__((ext_vector_type(4)));

__global__ __launch_bounds__(256) void Augment_fast4(
    const f32x4* __restrict__ x4, f32x4* __restrict__ out4,
    const float c, const float s)
{
    const float cc = 63.5f;
    const long tid    = (long)blockIdx.x * blockDim.x + threadIdx.x;
    const long stride = (long)gridDim.x * blockDim.x;

    long srcidx[4];
    bool ok[4];
#pragma unroll
    for (int k = 0; k < 4; ++k) {
        long o4 = tid + (long)k * stride;
        int f4 = (int)(o4 & 1);
        int d  = (int)((o4 >> 1) & 127);
        int j  = (int)((o4 >> 8) & 127);
        int i  = (int)((o4 >> 15) & 127);
        int b  = (int)(o4 >> 22);

        int i1 = (i - 7) & 127;
        int j1 = (140 - j) & 127;

        float dx = (float)j1 - cc;
        float dy = (float)i1 - cc;
        float sx = __fadd_rn(__fsub_rn(__fmul_rn(c, dx), __fmul_rn(s, dy)), cc);
        float sy = __fadd_rn(__fadd_rn(__fmul_rn(s, dx), __fmul_rn(c, dy)), cc);
        int ix = (int)rintf(sx);
        int iy = (int)rintf(sy);

        ok[k] = ((unsigned)ix < 128u) && ((unsigned)iy < 128u);
        srcidx[k] = ((((long)b * 128 + iy) * 128 + ix) * 128 + (127 - d)) * 2 + f4;
    }

    f32x4 v[4];
#pragma unroll
    for (int k = 0; k < 4; ++k) {
        v[k] = (f32x4)(0.f);
        if (ok[k]) v[k] = x4[srcidx[k]];   // wave-uniform condition (same i,j per wave)
    }
#pragma unroll
    for (int k = 0; k < 4; ++k) {
        __builtin_nontemporal_store(v[k], &out4[tid + (long)k * stride]);
    }
}

// Generic fallback (any size): R1 kernel.
__global__ __launch_bounds__(256) void Augment_generic(
    const float* __restrict__ x, float* __restrict__ out,
    const float c, const float s, const long total4)
{
    const float cc = 63.5f;
    long idx    = (long)blockIdx.x * blockDim.x + threadIdx.x;
    long stride = (long)gridDim.x * blockDim.x;
    for (long o4 = idx; o4 < total4; o4 += stride) {
        int f4 = (int)(o4 & 1);
        int d  = (int)((o4 >> 1) & 127);
        int j  = (int)((o4 >> 8) & 127);
        int i  = (int)((o4 >> 15) & 127);
        int b  = (int)(o4 >> 22);
        int i1 = (i - 7) & 127;
        int j1 = (140 - j) & 127;
        float dx = (float)j1 - cc;
        float dy = (float)i1 - cc;
        float sx = __fadd_rn(__fsub_rn(__fmul_rn(c, dx), __fmul_rn(s, dy)), cc);
        float sy = __fadd_rn(__fadd_rn(__fmul_rn(s, dx), __fmul_rn(c, dy)), cc);
        int ix = (int)rintf(sx);
        int iy = (int)rintf(sy);
        float4 v = make_float4(0.f, 0.f, 0.f, 0.f);
        if (((unsigned)ix < 128u) && ((unsigned)iy < 128u)) {
            long src4 = ((((long)b * 128 + iy) * 128 + ix) * 128 + (127 - d)) * 2 + f4;
            v = ((const float4*)x)[src4];
        }
        ((float4*)out)[o4] = v;
    }
}

extern "C" void kernel_launch(void* const* d_in, const int* in_sizes, int n_in,
                              void* d_out, int out_size, void* d_ws, size_t ws_size,
                              hipStream_t stream) {
    const float* x = (const float*)d_in[0];
    float* out = (float*)d_out;

    float deg2rad_c = (float)(M_PI / 180.0);
    float theta = 80.0f * deg2rad_c;          // f32(80) * f32(pi/180), as jnp does
    float c = (float)cos((double)theta);
    float s = (float)sin((double)theta);

    long total4 = (long)out_size / 4;
    const int block = 256;
    const int UNROLL = 4;
    if (total4 % (block * UNROLL) == 0) {
        int grid = (int)(total4 / (block * UNROLL));   // 8192 for the bench shape
        hipLaunchKernelGGL(Augment_fast4, dim3(grid), dim3(block), 0, stream,
                           (const f32x4*)x, (f32x4*)out, c, s);
    } else {
        int grid = 2048;
        hipLaunchKernelGGL(Augment_generic, dim3(grid), dim3(block), 0, stream,
                           x, out, c, s, total4);
    }
}

// Round 4
// 41.889 us; speedup vs baseline: 1.0662x; 1.0080x over previous
//
#include <hip/hip_runtime.h>
#include <math.h>

// out[b,i,j,d,f] = valid(i1,j1) ? x[b, iy(i1,j1), ix(i1,j1), 127-d, f] : 0
//   i1 = (i-7) & 127, j1 = (140-j) & 127, dsrc = 127-d
// Each wave owns whole 4KB [D,F] slabs: source slab is one contiguous 4KB
// granule (d-reversed), dest slab contiguous. 2 pixels per wave for MLP.
// Rotation math replicates jnp float32 ops exactly (no FMA, rintf = half-even).

typedef float f32x4 __attribute__((ext_vector_type(4)));

__global__ __launch_bounds__(256) void Augment_slab(
    const f32x4* __restrict__ x4, f32x4* __restrict__ out4,
    const float c, const float s)
{
    const float cc = 63.5f;
    const int lane = threadIdx.x & 63;
    const int wid  = threadIdx.x >> 6;
    // 2 pixels per wave: pixel ids p0, p0+1
    const int p0 = (blockIdx.x * 4 + wid) * 2;

    f32x4 v[2][4];
#pragma unroll
    for (int t = 0; t < 2; ++t) {
        const int p = p0 + t;
        const int j = p & 127;
        const int i = (p >> 7) & 127;
        const int b = p >> 14;

        const int i1 = (i - 7) & 127;
        const int j1 = (140 - j) & 127;
        const float dx = (float)j1 - cc;
        const float dy = (float)i1 - cc;
        const float sx = __fadd_rn(__fsub_rn(__fmul_rn(c, dx), __fmul_rn(s, dy)), cc);
        const float sy = __fadd_rn(__fadd_rn(__fmul_rn(s, dx), __fmul_rn(c, dy)), cc);
        const int ixs = (int)rintf(sx);
        const int iys = (int)rintf(sy);
        const bool ok = ((unsigned)ixs < 128u) && ((unsigned)iys < 128u);

#pragma unroll
        for (int k = 0; k < 4; ++k) v[t][k] = (f32x4)(0.f);
        if (ok) {
            const long srcbase = (((long)b * 16384) + (long)iys * 128 + ixs) * 256;
#pragma unroll
            for (int k = 0; k < 4; ++k) {
                const int q = k * 64 + lane;          // linear offset in dst slab
                const int srcq = 254 - q + 2 * (q & 1); // d-flip, f preserved
                v[t][k] = x4[srcbase + srcq];
            }
        }
    }
#pragma unroll
    for (int t = 0; t < 2; ++t) {
        const long dstbase = (long)(p0 + t) * 256;
#pragma unroll
        for (int k = 0; k < 4; ++k)
            __builtin_nontemporal_store(v[t][k], &out4[dstbase + k * 64 + lane]);
    }
}

// Generic fallback (any size): R1 kernel.
__global__ __launch_bounds__(256) void Augment_generic(
    const float* __restrict__ x, float* __restrict__ out,
    const float c, const float s, const long total4)
{
    const float cc = 63.5f;
    long idx    = (long)blockIdx.x * blockDim.x + threadIdx.x;
    long stride = (long)gridDim.x * blockDim.x;
    for (long o4 = idx; o4 < total4; o4 += stride) {
        int f4 = (int)(o4 & 1);
        int d  = (int)((o4 >> 1) & 127);
        int j  = (int)((o4 >> 8) & 127);
        int i  = (int)((o4 >> 15) & 127);
        int b  = (int)(o4 >> 22);
        int i1 = (i - 7) & 127;
        int j1 = (140 - j) & 127;
        float dx = (float)j1 - cc;
        float dy = (float)i1 - cc;
        float sx = __fadd_rn(__fsub_rn(__fmul_rn(c, dx), __fmul_rn(s, dy)), cc);
        float sy = __fadd_rn(__fadd_rn(__fmul_rn(s, dx), __fmul_rn(c, dy)), cc);
        int ixs = (int)rintf(sx);
        int iys = (int)rintf(sy);
        float4 v = make_float4(0.f, 0.f, 0.f, 0.f);
        if (((unsigned)ixs < 128u) && ((unsigned)iys < 128u)) {
            long src4 = ((((long)b * 128 + iys) * 128 + ixs) * 128 + (127 - d)) * 2 + f4;
            v = ((const float4*)x)[src4];
        }
        ((float4*)out)[o4] = v;
    }
}

extern "C" void kernel_launch(void* const* d_in, const int* in_sizes, int n_in,
                              void* d_out, int out_size, void* d_ws, size_t ws_size,
                              hipStream_t stream) {
    const float* x = (const float*)d_in[0];
    float* out = (float*)d_out;

    float deg2rad_c = (float)(M_PI / 180.0);
    float theta = 80.0f * deg2rad_c;          // f32(80) * f32(pi/180), as jnp does
    float c = (float)cos((double)theta);
    float s = (float)sin((double)theta);

    long total4 = (long)out_size / 4;
    long pixels = total4 / 256;               // 4KB slabs ([D=128,F=8] per pixel)
    // slab kernel needs: out divisible into 4KB slabs, 8 pixels per block
    if ((long)out_size % 1024 == 0 && pixels % 8 == 0) {
        int grid = (int)(pixels / 8);         // 4096 for the bench shape
        hipLaunchKernelGGL(Augment_slab, dim3(grid), dim3(256), 0, stream,
                           (const f32x4*)x, (f32x4*)out, c, s);
    } else {
        hipLaunchKernelGGL(Augment_generic, dim3(2048), dim3(256), 0, stream,
                           x, out, c, s, total4);
    }
}

// Round 6
// 41.837 us; speedup vs baseline: 1.0675x; 1.0012x over previous
//
#include <hip/hip_runtime.h>
#include <math.h>

// out[b,i,j,d,f] = valid(i1,j1) ? x[b, iy(i1,j1), ix(i1,j1), 127-d, f] : 0
//   i1 = (i-7) & 127, j1 = (140-j) & 127, dsrc = 127-d
// Slab form: each wave owns whole 4KB [D,F] slabs (contiguous src granule,
// contiguous dst), 2 pixels per wave for MLP.
// Rotation math replicates jnp float32 ops exactly (no FMA, rintf = half-even).
// R5 post-mortem: inline-asm `nt sc1` stores corrupt data; `nt` builtin has no
// MALL effect (memory-side cache). This is the R4 kernel, which sits at the
// float4-copy roofline (268 MB moved @ 6.4 TB/s >= 6.29 TB/s m13 ceiling).

typedef float f32x4 __attribute__((ext_vector_type(4)));

__global__ __launch_bounds__(256) void Augment_slab(
    const f32x4* __restrict__ x4, f32x4* __restrict__ out4,
    const float c, const float s)
{
    const float cc = 63.5f;
    const int lane = threadIdx.x & 63;
    const int wid  = threadIdx.x >> 6;
    const int p0 = (blockIdx.x * 4 + wid) * 2;   // 2 pixels per wave

    f32x4 v[2][4];
#pragma unroll
    for (int t = 0; t < 2; ++t) {
        const int p = p0 + t;
        const int j = p & 127;
        const int i = (p >> 7) & 127;
        const int b = p >> 14;

        const int i1 = (i - 7) & 127;
        const int j1 = (140 - j) & 127;
        const float dx = (float)j1 - cc;
        const float dy = (float)i1 - cc;
        const float sx = __fadd_rn(__fsub_rn(__fmul_rn(c, dx), __fmul_rn(s, dy)), cc);
        const float sy = __fadd_rn(__fadd_rn(__fmul_rn(s, dx), __fmul_rn(c, dy)), cc);
        const int ixs = (int)rintf(sx);
        const int iys = (int)rintf(sy);
        const bool ok = ((unsigned)ixs < 128u) && ((unsigned)iys < 128u);

#pragma unroll
        for (int k = 0; k < 4; ++k) v[t][k] = (f32x4)(0.f);
        if (ok) {
            const long srcbase = (((long)b * 16384) + (long)iys * 128 + ixs) * 256;
#pragma unroll
            for (int k = 0; k < 4; ++k) {
                const int q = k * 64 + lane;            // linear offset in dst slab
                const int srcq = 254 - q + 2 * (q & 1); // d-flip, f preserved
                v[t][k] = x4[srcbase + srcq];
            }
        }
    }
#pragma unroll
    for (int t = 0; t < 2; ++t) {
        const long dstbase = (long)(p0 + t) * 256;
#pragma unroll
        for (int k = 0; k < 4; ++k)
            __builtin_nontemporal_store(v[t][k], &out4[dstbase + k * 64 + lane]);
    }
}

// Generic fallback (any size): R1 kernel.
__global__ __launch_bounds__(256) void Augment_generic(
    const float* __restrict__ x, float* __restrict__ out,
    const float c, const float s, const long total4)
{
    const float cc = 63.5f;
    long idx    = (long)blockIdx.x * blockDim.x + threadIdx.x;
    long stride = (long)gridDim.x * blockDim.x;
    for (long o4 = idx; o4 < total4; o4 += stride) {
        int f4 = (int)(o4 & 1);
        int d  = (int)((o4 >> 1) & 127);
        int j  = (int)((o4 >> 8) & 127);
        int i  = (int)((o4 >> 15) & 127);
        int b  = (int)(o4 >> 22);
        int i1 = (i - 7) & 127;
        int j1 = (140 - j) & 127;
        float dx = (float)j1 - cc;
        float dy = (float)i1 - cc;
        float sx = __fadd_rn(__fsub_rn(__fmul_rn(c, dx), __fmul_rn(s, dy)), cc);
        float sy = __fadd_rn(__fadd_rn(__fmul_rn(s, dx), __fmul_rn(c, dy)), cc);
        int ixs = (int)rintf(sx);
        int iys = (int)rintf(sy);
        float4 v = make_float4(0.f, 0.f, 0.f, 0.f);
        if (((unsigned)ixs < 128u) && ((unsigned)iys < 128u)) {
            long src4 = ((((long)b * 128 + iys) * 128 + ixs) * 128 + (127 - d)) * 2 + f4;
            v = ((const float4*)x)[src4];
        }
        ((float4*)out)[o4] = v;
    }
}

extern "C" void kernel_launch(void* const* d_in, const int* in_sizes, int n_in,
                              void* d_out, int out_size, void* d_ws, size_t ws_size,
                              hipStream_t stream) {
    const float* x = (const float*)d_in[0];
    float* out = (float*)d_out;

    float deg2rad_c = (float)(M_PI / 180.0);
    float theta = 80.0f * deg2rad_c;          // f32(80) * f32(pi/180), as jnp does
    float c = (float)cos((double)theta);
    float s = (float)sin((double)theta);

    long total4 = (long)out_size / 4;
    long pixels = total4 / 256;               // 4KB slabs ([D=128,F=8] per pixel)
    if ((long)out_size % 1024 == 0 && pixels % 8 == 0) {
        int grid = (int)(pixels / 8);         // 4096 for the bench shape
        hipLaunchKernelGGL(Augment_slab, dim3(grid), dim3(256), 0, stream,
                           (const f32x4*)x, (f32x4*)out, c, s);
    } else {
        hipLaunchKernelGGL(Augment_generic, dim3(2048), dim3(256), 0, stream,
                           x, out, c, s, total4);
    }
}